// Round 1
// 1148.677 us; speedup vs baseline: 1.1692x; 1.1692x over previous
//
#include <hip/hip_runtime.h>
#include <hip/hip_bf16.h>

// Problem constants
#define DIM   4096
#define SEQ   2048
#define NH    32
#define HD    128
#define BSZ   2
#define SEG   16777216   // 4096*4096 elements (x, each weight, each activation)

typedef unsigned short u16;
typedef unsigned int   u32;
typedef __attribute__((ext_vector_type(8))) short bf16x8;
typedef __attribute__((ext_vector_type(4))) float f32x4;
typedef __attribute__((ext_vector_type(4))) u16   u16x4;

__device__ __forceinline__ float b2f(u16 u) {
    union { u32 i; float f; } c; c.i = ((u32)u) << 16; return c.f;
}
__device__ __forceinline__ u16 f2b(float f) {
    u32 x = __float_as_uint(f);
    return (u16)((x + 0x7FFFu + ((x >> 16) & 1u)) >> 16);  // RNE
}
__device__ __forceinline__ void gload_lds16(const void* g, void* l) {
    __builtin_amdgcn_global_load_lds(
        (__attribute__((address_space(1))) void*)(unsigned long)(g),
        (__attribute__((address_space(3))) void*)(l), 16, 0, 0);
}

// ---------------------------------------------------------------------------
// 1) cast x + wq + wk + wv + wo (fp32) -> bf16, contiguous into ws segments 0..4
// ---------------------------------------------------------------------------
__global__ __launch_bounds__(256) void cast5(const float* __restrict__ x,
                                             const float* __restrict__ wq,
                                             const float* __restrict__ wk,
                                             const float* __restrict__ wv,
                                             const float* __restrict__ wo,
                                             u16* __restrict__ dst) {
    int i = blockIdx.x * 1024 + threadIdx.x * 4;   // 4 elems per thread
    int seg = i >> 24;                              // SEG == 2^24
    int off = i & (SEG - 1);
    const float* s = x;
    if (seg == 1) s = wq; else if (seg == 2) s = wk;
    else if (seg == 3) s = wv; else if (seg == 4) s = wo;
    float4 v = *(const float4*)(s + off);
    u16x4 o; o.x = f2b(v.x); o.y = f2b(v.y); o.z = f2b(v.z); o.w = f2b(v.w);
    *(u16x4*)(dst + i) = o;
}

// ---------------------------------------------------------------------------
// 2) GEMM  C[M,N] = A[M,K] * B[N,K]^T   (bf16 in, bf16 or fp32 out)
//    256x256 tile, BK=64, 8 waves (2M x 4N), 8-phase counted-vmcnt schedule
//    (T2 st-swizzle + T3/T4 counted vmcnt + T5 setprio per the 8-phase
//    template). LDS = 8 x 16KiB half-tile chunks [dbuf][Ah0,Ah1,Bh0,Bh1],
//    double-buffered over K-tiles. Staging: linear gload_lds dest +
//    inverse-swizzled global source; ds_read applies the same swizzle:
//    swz(byte) = byte ^ (((byte>>8)&3)<<4)  (involution within 16KiB chunk).
//    grid: (N/256, M/256, nz); B/C advanced by z*SEG.
// ---------------------------------------------------------------------------
#define BARRIER() do { asm volatile("" ::: "memory"); \
                       __builtin_amdgcn_s_barrier(); \
                       asm volatile("" ::: "memory"); } while (0)

template<int OUT_BF16>
__global__ __launch_bounds__(512, 2) void gemm8p(const u16* __restrict__ A,
                                                 const u16* __restrict__ Bbase,
                                                 void* __restrict__ Cv) {
    __shared__ __align__(16) char lds[131072];   // 128 KiB

    const int tid = threadIdx.x;
    const int lane = tid & 63, w = tid >> 6;     // 8 waves
    const int quad = lane >> 4, m16 = lane & 15;
    const int wm = w >> 2, wn = w & 3;           // wave tile: 128 rows x 64 cols
    const int m0 = blockIdx.y * 256, n0 = blockIdx.x * 256;
    const u16* Bp = Bbase + (size_t)blockIdx.z * SEG;

    // --- staging source decode: LDS linear byte p  <-  element at swz(p) ---
    const u16* aSrc[2];
    const u16* bSrc[2];
#pragma unroll
    for (int i = 0; i < 2; ++i) {
        int p = i * 8192 + w * 1024 + lane * 16;           // byte in 16KiB chunk
        int q = p ^ (((p >> 8) & 3) << 4);                  // inverse swizzle
        int rowoff = (q >> 11) * 16 + ((q >> 6) & 15);      // r16g*16 + r
        int coloff = (((q >> 10) & 1) << 5) + ((q & 63) >> 1); // c32g*32 + c
        aSrc[i] = A  + (size_t)(m0 + rowoff) * DIM + coloff;
        bSrc[i] = Bp + (size_t)(n0 + rowoff) * DIM + coloff;
    }
    // per-lane swizzled ds_read byte offset within a chunk
    const int laneoff = m16 * 64 + ((quad * 16) ^ (((m16 >> 2) & 3) << 4));

    f32x4 acc[8][4];
#pragma unroll
    for (int a = 0; a < 8; ++a)
#pragma unroll
        for (int b = 0; b < 4; ++b) acc[a][b] = 0.f;

    bf16x8 af[4][2];   // current m-half fragments (4 mt x 2 ks)
    bf16x8 bfr[4][2];  // all 4 n-frags of this wave (nt x ks)

// chunk ids: (d*4 + 0/1) = A half0/1 ; (d*4 + 2 + 0/1) = B half0/1
#define STAGE_A(d, h, kt) do { int kk_ = ((kt) & 63) * 64;                       \
    gload_lds16(aSrc[0] + (size_t)(h) * (128 * DIM) + kk_,                       \
                lds + ((d) * 4 + (h)) * 16384 + w * 1024);                       \
    gload_lds16(aSrc[1] + (size_t)(h) * (128 * DIM) + kk_,                       \
                lds + ((d) * 4 + (h)) * 16384 + 8192 + w * 1024); } while (0)
#define STAGE_B(d, h, kt) do { int kk_ = ((kt) & 63) * 64;                       \
    gload_lds16(bSrc[0] + (size_t)(h) * (128 * DIM) + kk_,                       \
                lds + ((d) * 4 + 2 + (h)) * 16384 + w * 1024);                   \
    gload_lds16(bSrc[1] + (size_t)(h) * (128 * DIM) + kk_,                       \
                lds + ((d) * 4 + 2 + (h)) * 16384 + 8192 + w * 1024); } while (0)
#define LOAD_A(d, mh) do {                                                       \
    const char* base_ = lds + ((d) * 4 + wm) * 16384 + (mh) * 8192 + laneoff;    \
    _Pragma("unroll") for (int mt = 0; mt < 4; ++mt)                             \
    _Pragma("unroll") for (int ks = 0; ks < 2; ++ks)                             \
        af[mt][ks] = *(const bf16x8*)(base_ + mt * 2048 + ks * 1024); } while (0)
#define LOAD_B(d, nh) do {                                                       \
    const char* base_ = lds + ((d) * 4 + 2 + (wn >> 1)) * 16384                  \
                        + (wn & 1) * 8192 + (nh) * 4096 + laneoff;               \
    _Pragma("unroll") for (int nt = 0; nt < 2; ++nt)                             \
    _Pragma("unroll") for (int ks = 0; ks < 2; ++ks)                             \
        bfr[(nh) * 2 + nt][ks] = *(const bf16x8*)(base_ + nt * 2048 + ks * 1024);\
    } while (0)
#define MFMA_Q(mh, nh) do {                                                      \
    _Pragma("unroll") for (int mt = 0; mt < 4; ++mt)                             \
    _Pragma("unroll") for (int nt = 0; nt < 2; ++nt)                             \
    _Pragma("unroll") for (int ks = 0; ks < 2; ++ks)                             \
        acc[(mh) * 4 + mt][(nh) * 2 + nt] =                                      \
            __builtin_amdgcn_mfma_f32_16x16x32_bf16(                             \
                af[mt][ks], bfr[(nh) * 2 + nt][ks],                              \
                acc[(mh) * 4 + mt][(nh) * 2 + nt], 0, 0, 0); } while (0)

    // prologue: tile0 fully + tile1 B halves; force tile0 landed (residue = t1.B)
    STAGE_B(0, 0, 0); STAGE_B(0, 1, 0); STAGE_A(0, 0, 0); STAGE_A(0, 1, 0);
    STAGE_B(1, 0, 1); STAGE_B(1, 1, 1);
    asm volatile("s_waitcnt vmcnt(4)" ::: "memory");
    BARRIER();

    for (int it = 0; it < 32; ++it) {           // 2 K-tiles / iter, 64 tiles
        const int t = 2 * it;
        // ---- P1: reads tile t (a-lo, b-lo); stage (t+1).Ah0 -> buf1
        LOAD_A(0, 0); LOAD_B(0, 0);
        STAGE_A(1, 0, t + 1);
        asm volatile("s_waitcnt lgkmcnt(8)" ::: "memory");
        BARRIER();
        asm volatile("s_waitcnt lgkmcnt(0)" ::: "memory");
        __builtin_amdgcn_s_setprio(1); MFMA_Q(0, 0); __builtin_amdgcn_s_setprio(0);
        BARRIER();
        // ---- P2: b-hi; stage (t+1).Ah1 -> buf1
        LOAD_B(0, 1);
        STAGE_A(1, 1, t + 1);
        BARRIER();
        asm volatile("s_waitcnt lgkmcnt(0)" ::: "memory");
        __builtin_amdgcn_s_setprio(1); MFMA_Q(0, 1); __builtin_amdgcn_s_setprio(0);
        BARRIER();
        // ---- P3: a-hi; stage (t+2).Bh0 -> buf0 (buf0.B reads done after P2)
        LOAD_A(0, 1);
        STAGE_B(0, 0, t + 2);
        BARRIER();
        asm volatile("s_waitcnt lgkmcnt(0)" ::: "memory");
        __builtin_amdgcn_s_setprio(1); MFMA_Q(1, 1); __builtin_amdgcn_s_setprio(0);
        BARRIER();
        // ---- P4: stage (t+2).Bh1; vmcnt(4) forces tile t+1 fully landed
        STAGE_B(0, 1, t + 2);
        BARRIER();
        __builtin_amdgcn_s_setprio(1); MFMA_Q(1, 0); __builtin_amdgcn_s_setprio(0);
        asm volatile("s_waitcnt vmcnt(4)" ::: "memory");
        BARRIER();
        // ---- P5: reads tile t+1; stage (t+2).Ah0 -> buf0 (buf0.A free after P3)
        LOAD_A(1, 0); LOAD_B(1, 0);
        STAGE_A(0, 0, t + 2);
        asm volatile("s_waitcnt lgkmcnt(8)" ::: "memory");
        BARRIER();
        asm volatile("s_waitcnt lgkmcnt(0)" ::: "memory");
        __builtin_amdgcn_s_setprio(1); MFMA_Q(0, 0); __builtin_amdgcn_s_setprio(0);
        BARRIER();
        // ---- P6: stage (t+2).Ah1
        LOAD_B(1, 1);
        STAGE_A(0, 1, t + 2);
        BARRIER();
        asm volatile("s_waitcnt lgkmcnt(0)" ::: "memory");
        __builtin_amdgcn_s_setprio(1); MFMA_Q(0, 1); __builtin_amdgcn_s_setprio(0);
        BARRIER();
        // ---- P7: stage (t+3).Bh0 -> buf1 (buf1.B reads done after P6)
        LOAD_A(1, 1);
        STAGE_B(1, 0, t + 3);
        BARRIER();
        asm volatile("s_waitcnt lgkmcnt(0)" ::: "memory");
        __builtin_amdgcn_s_setprio(1); MFMA_Q(1, 1); __builtin_amdgcn_s_setprio(0);
        BARRIER();
        // ---- P8: stage (t+3).Bh1; vmcnt(4) forces tile t+2 fully landed
        STAGE_B(1, 1, t + 3);
        BARRIER();
        __builtin_amdgcn_s_setprio(1); MFMA_Q(1, 0); __builtin_amdgcn_s_setprio(0);
        asm volatile("s_waitcnt vmcnt(4)" ::: "memory");
        BARRIER();
    }
    asm volatile("s_waitcnt vmcnt(0)" ::: "memory");  // drain tail garbage stages

#pragma unroll
    for (int mt = 0; mt < 8; ++mt)
#pragma unroll
        for (int nt = 0; nt < 4; ++nt) {
            const int row = m0 + wm * 128 + mt * 16 + quad * 4;
            const int col = n0 + wn * 64 + nt * 16 + m16;
            if (OUT_BF16) {
                u16* C = (u16*)Cv + (size_t)blockIdx.z * SEG;
#pragma unroll
                for (int r = 0; r < 4; ++r)
                    C[(size_t)(row + r) * DIM + col] = f2b(acc[mt][nt][r]);
            } else {
                float* C = (float*)Cv + (size_t)blockIdx.z * SEG;
#pragma unroll
                for (int r = 0; r < 4; ++r)
                    C[(size_t)(row + r) * DIM + col] = acc[mt][nt][r];
            }
        }
#undef STAGE_A
#undef STAGE_B
#undef LOAD_A
#undef LOAD_B
#undef MFMA_Q
}

// ---------------------------------------------------------------------------
// 3) RoPE on xq, xk. Writes q_b, k_b (bf16) and new_hidden[0] (fp32).
// ---------------------------------------------------------------------------
__global__ __launch_bounds__(256) void rope(const u16* __restrict__ XQ,
                                            const u16* __restrict__ XK,
                                            const float* __restrict__ FC,
                                            u16* __restrict__ Qo,
                                            u16* __restrict__ Ko,
                                            float* __restrict__ KH) {
    int tid = blockIdx.x * 256 + threadIdx.x;   // ((b*S+s)*NH+h)*64 + i
    int i = tid & 63;
    int s = (tid >> 11) & 2047;
    float2 cs = *(const float2*)(FC + (s * 64 + i) * 2);
    u32 q = ((const u32*)XQ)[tid];
    u32 k = ((const u32*)XK)[tid];
    float q0 = b2f((u16)(q & 0xffff)), q1 = b2f((u16)(q >> 16));
    float k0 = b2f((u16)(k & 0xffff)), k1 = b2f((u16)(k >> 16));
    float qr = q0 * cs.x - q1 * cs.y, qi = q0 * cs.y + q1 * cs.x;
    float kr = k0 * cs.x - k1 * cs.y, ki = k0 * cs.y + k1 * cs.x;
    ((u32*)Qo)[tid] = (u32)f2b(qr) | ((u32)f2b(qi) << 16);
    ((u32*)Ko)[tid] = (u32)f2b(kr) | ((u32)f2b(ki) << 16);
    *(float2*)(KH + (size_t)tid * 2) = make_float2(kr, ki);
}

// ---------------------------------------------------------------------------
// 4) V prep: new_hidden[1] (fp32) + transposed Vt (bf16, [bh][d][s])
// ---------------------------------------------------------------------------
__global__ __launch_bounds__(256) void vprep(const u16* __restrict__ XV,
                                             float* __restrict__ VH,
                                             u16* __restrict__ VT) {
    __shared__ u16 tile[64][65];
    int bs = blockIdx.x;        // s-tile (32)
    int bd = blockIdx.y;        // d-tile (2)
    int bh = blockIdx.z;        // (64)
    int b = bh >> 5, h = bh & 31;
    int t = threadIdx.x;
    int c = t & 63, r4 = t >> 6;
    for (int i = 0; i < 16; ++i) {
        int sr = i * 4 + r4;
        int gi = ((b * SEQ + bs * 64 + sr) * NH + h) * HD + bd * 64 + c;
        u16 v = XV[gi];
        VH[gi] = b2f(v);
        tile[sr][c] = v;
    }
    __syncthreads();
    for (int i = 0; i < 16; ++i) {
        int dr = i * 4 + r4;
        VT[(bh * HD + bd * 64 + dr) * SEQ + bs * 64 + c] = tile[c][dr];
    }
}

// ---------------------------------------------------------------------------
// 5) Causal flash attention v2.
//    Block = 128 q-rows, 4 waves x 32 rows (2 m-frags). KV tile = 64.
//    K/V staged by global_load_lds (XOR chunk swizzle, unpadded layouts).
// ---------------------------------------------------------------------------
__global__ __launch_bounds__(256, 2) void flash(const u16* __restrict__ Q,
                                                const u16* __restrict__ K,
                                                const u16* __restrict__ Vt,
                                                u16* __restrict__ O) {
    __shared__ __align__(16) u16 k_lds[64 * 128];
    __shared__ __align__(16) u16 v_lds[128 * 64];
    __shared__ __align__(16) u16 p_lds[4][32 * 68];

    const int tid = threadIdx.x, lane = tid & 63, w = tid >> 6;
    const int quad = lane >> 4, m16 = lane & 15;
    const int bh = blockIdx.x;                 // 0..63
    const int b = bh >> 5, h = bh & 31;
    const int qt = (gridDim.y - 1) - blockIdx.y;   // long blocks dispatch first
    const int q0 = qt * 128;
    const int wrow = q0 + w * 32;              // this wave's 32 q-rows

    const int gk = w * 256 + lane;             // K granule base (j adds 64)
    bf16x8 qa[2][4];
#pragma unroll
    for (int mt = 0; mt < 2; ++mt) {
        const u16* qp = Q + ((size_t)(b * SEQ + wrow + mt * 16 + m16) * NH + h) * HD;
#pragma unroll
        for (int ks = 0; ks < 4; ++ks) qa[mt][ks] = *(const bf16x8*)(qp + ks * 32 + quad * 8);
    }

    float mi[2][4], li[2][4];
    f32x4 o[2][8];
#pragma unroll
    for (int mt = 0; mt < 2; ++mt)
#pragma unroll
        for (int r = 0; r < 4; ++r) { mi[mt][r] = -1e30f; li[mt][r] = 0.f; }
#pragma unroll
    for (int mt = 0; mt < 2; ++mt)
#pragma unroll
        for (int n = 0; n < 8; ++n) o[mt][n] = 0.f;

    const float scale = 0.08838834764831845f;   // 1/sqrt(128)
    const int nkt = 2 * qt + 2;

    const u16* Kbase = K + ((size_t)(b * SEQ) * NH + h) * HD;
    const u16* Vbase = Vt + (size_t)(bh * HD) * SEQ;

    for (int kt = 0; kt < nkt; ++kt) {
        const int k0 = kt * 64;
        __syncthreads();
#pragma unroll
        for (int j = 0; j < 4; ++j) {
            int g = gk + j * 64;
            int r = g >> 4, p = g & 15, c = p ^ (r & 15);
            gload_lds16(Kbase + (size_t)(k0 + r) * DIM + c * 8,
                        (char*)k_lds + w * 4096 + j * 1024);
        }
#pragma unroll
        for (int j = 0; j < 4; ++j) {
            int g = gk + j * 64;
            int r = g >> 3, p = g & 7, c = p ^ (r & 7);
            gload_lds16(Vbase + (size_t)r * SEQ + k0 + c * 8,
                        (char*)v_lds + w * 4096 + j * 1024);
        }
        __syncthreads();

        if (k0 > wrow + 31) continue;   // fully-masked for this wave (uniform)

        f32x4 s[2][4];
#pragma unroll
        for (int mt = 0; mt < 2; ++mt)
#pragma unroll
            for (int nt = 0; nt < 4; ++nt) s[mt][nt] = 0.f;
#pragma unroll
        for (int ks = 0; ks < 4; ++ks)
#pragma unroll
            for (int nt = 0; nt < 4; ++nt) {
                int rk = nt * 16 + m16;
                int p = (ks * 4 + quad) ^ m16;
                bf16x8 kb = *(const bf16x8*)(k_lds + rk * 128 + p * 8);
#pragma unroll
                for (int mt = 0; mt < 2; ++mt)
                    s[mt][nt] = __builtin_amdgcn_mfma_f32_16x16x32_bf16(
                        qa[mt][ks], kb, s[mt][nt], 0, 0, 0);
            }

#pragma unroll
        for (int mt = 0; mt < 2; ++mt) {
            float sv[4][4];
            const bool need_mask = (k0 + 63) > (wrow + mt * 16);
#pragma unroll
            for (int nt = 0; nt < 4; ++nt)
#pragma unroll
                for (int r = 0; r < 4; ++r) {
                    float v = s[mt][nt][r] * scale;
                    if (need_mask) {
                        int col = k0 + nt * 16 + m16;
                        int rq = wrow + mt * 16 + quad * 4 + r;
                        if (col > rq) v = -1e30f;
                    }
                    sv[nt][r] = v;
                }
#pragma unroll
            for (int r = 0; r < 4; ++r) {
                float mx = fmaxf(fmaxf(sv[0][r], sv[1][r]), fmaxf(sv[2][r], sv[3][r]));
#pragma unroll
                for (int off = 8; off >= 1; off >>= 1) mx = fmaxf(mx, __shfl_xor(mx, off));
                float mnew = fmaxf(mi[mt][r], mx);
                float alpha = __expf(mi[mt][r] - mnew);
                float sum = 0.f;
#pragma unroll
                for (int nt = 0; nt < 4; ++nt) {
                    float pv = __expf(sv[nt][r] - mnew);
                    sum += pv;
                    p_lds[w][(mt * 16 + quad * 4 + r) * 68 + nt * 16 + m16] = f2b(pv);
                }
#pragma unroll
                for (int off = 8; off >= 1; off >>= 1) sum += __shfl_xor(sum, off);
                li[mt][r] = li[mt][r] * alpha + sum;
                mi[mt][r] = mnew;
#pragma unroll
                for (int n8 = 0; n8 < 8; ++n8) o[mt][n8][r] *= alpha;
            }
        }

        asm volatile("s_waitcnt lgkmcnt(0)" ::: "memory");

#pragma unroll
        for (int ks2 = 0; ks2 < 2; ++ks2) {
            bf16x8 pa[2];
#pragma unroll
            for (int mt = 0; mt < 2; ++mt)
                pa[mt] = *(const bf16x8*)(&p_lds[w][0] + (mt * 16 + m16) * 68 + ks2 * 32 + quad * 8);
#pragma unroll
            for (int n8 = 0; n8 < 8; ++n8) {
                int rv = n8 * 16 + m16;
                int p = (ks2 * 4 + quad) ^ (m16 & 7);
                bf16x8 vb = *(const bf16x8*)(v_lds + rv * 64 + p * 8);
#pragma unroll
                for (int mt = 0; mt < 2; ++mt)
                    o[mt][n8] = __builtin_amdgcn_mfma_f32_16x16x32_bf16(
                        pa[mt], vb, o[mt][n8], 0, 0, 0);
            }
        }
    }

#pragma unroll
    for (int mt = 0; mt < 2; ++mt) {
        float inv[4];
#pragma unroll
        for (int r = 0; r < 4; ++r) inv[r] = 1.0f / li[mt][r];
#pragma unroll
        for (int n8 = 0; n8 < 8; ++n8)
#pragma unroll
            for (int r = 0; r < 4; ++r) {
                int rq = wrow + mt * 16 + quad * 4 + r;
                O[((size_t)(b * SEQ + rq) * NH + h) * HD + n8 * 16 + m16] =
                    f2b(o[mt][n8][r] * inv[r]);
            }
    }
}

// ---------------------------------------------------------------------------
// launch — ws layout (bf16 elems, SEG each):
//  0: x_b (→ q_rope)  1: wq_b (→ k_rope)  2: wk_b (→ Vt)  3: wv_b (→ attn_out)
//  4: wo_b  5: xq_b  6: xk_b  7: xv_b
// ---------------------------------------------------------------------------
extern "C" void kernel_launch(void* const* d_in, const int* in_sizes, int n_in,
                              void* d_out, int out_size, void* d_ws, size_t ws_size,
                              hipStream_t stream) {
    const float* x  = (const float*)d_in[0];
    const float* fc = (const float*)d_in[1];
    const float* wq = (const float*)d_in[4];
    const float* wk = (const float*)d_in[5];
    const float* wv = (const float*)d_in[6];
    const float* wo = (const float*)d_in[7];

    float* out = (float*)d_out;
    float* kh  = out + 16777216;             // new_hidden[0]
    float* vh  = out + 33554432;             // new_hidden[1]

    u16* ws = (u16*)d_ws;
    u16* xb  = ws + 0L * SEG;
    u16* wqb = ws + 1L * SEG;
    u16* wkb = ws + 2L * SEG;
    u16* wvb = ws + 3L * SEG;
    u16* wob = ws + 4L * SEG;
    u16* xqb = ws + 5L * SEG;
    u16* xkb = ws + 6L * SEG;
    u16* xvb = ws + 7L * SEG;
    u16* qro = xb;    // q after rope
    u16* kro = wqb;   // k after rope
    u16* vt  = wkb;   // transposed V
    u16* ao  = wvb;   // attention output

    cast5<<<dim3(81920), dim3(256), 0, stream>>>(x, wq, wk, wv, wo, ws);
    gemm8p<1><<<dim3(16, 16, 3), dim3(512), 0, stream>>>(xb, wqb, (void*)xqb);
    rope<<<dim3(32768), dim3(256), 0, stream>>>(xqb, xkb, fc, qro, kro, kh);
    vprep<<<dim3(32, 2, 64), dim3(256), 0, stream>>>(xvb, vh, vt);
    flash<<<dim3(64, 16), dim3(256), 0, stream>>>(qro, kro, vt, ao);
    gemm8p<0><<<dim3(16, 16, 1), dim3(512), 0, stream>>>(ao, wob, (void*)out);
}

// Round 2
// 1119.097 us; speedup vs baseline: 1.2001x; 1.0264x over previous
//
#include <hip/hip_runtime.h>
#include <hip/hip_bf16.h>

// Problem constants
#define DIM   4096
#define SEQ   2048
#define NH    32
#define HD    128
#define BSZ   2
#define SEG   16777216   // 4096*4096 elements (x, each weight, each activation)

typedef unsigned short u16;
typedef unsigned int   u32;
typedef __attribute__((ext_vector_type(8))) short bf16x8;
typedef __attribute__((ext_vector_type(4))) float f32x4;
typedef __attribute__((ext_vector_type(4))) u16   u16x4;

__device__ __forceinline__ float b2f(u16 u) {
    union { u32 i; float f; } c; c.i = ((u32)u) << 16; return c.f;
}
__device__ __forceinline__ u16 f2b(float f) {
    u32 x = __float_as_uint(f);
    return (u16)((x + 0x7FFFu + ((x >> 16) & 1u)) >> 16);  // RNE
}
__device__ __forceinline__ void gload_lds16(const void* g, void* l) {
    __builtin_amdgcn_global_load_lds(
        (__attribute__((address_space(1))) void*)(unsigned long)(g),
        (__attribute__((address_space(3))) void*)(l), 16, 0, 0);
}

// ---------------------------------------------------------------------------
// 1) cast x + wq + wk + wv + wo (fp32) -> bf16, contiguous into ws segments 0..4
// ---------------------------------------------------------------------------
__global__ __launch_bounds__(256) void cast5(const float* __restrict__ x,
                                             const float* __restrict__ wq,
                                             const float* __restrict__ wk,
                                             const float* __restrict__ wv,
                                             const float* __restrict__ wo,
                                             u16* __restrict__ dst) {
    int i = blockIdx.x * 1024 + threadIdx.x * 4;   // 4 elems per thread
    int seg = i >> 24;                              // SEG == 2^24
    int off = i & (SEG - 1);
    const float* s = x;
    if (seg == 1) s = wq; else if (seg == 2) s = wk;
    else if (seg == 3) s = wv; else if (seg == 4) s = wo;
    float4 v = *(const float4*)(s + off);
    u16x4 o; o.x = f2b(v.x); o.y = f2b(v.y); o.z = f2b(v.z); o.w = f2b(v.w);
    *(u16x4*)(dst + i) = o;
}

// ---------------------------------------------------------------------------
// 2) GEMM  C[M,N] = A[M,K] * B[N,K]^T   (bf16 in, bf16 or fp32 out)
//    256x256 tile, BK=64, 8 waves (2M x 4N), 8-phase counted-vmcnt schedule.
//    LDS = 8 x 16KiB half-tile chunks [dbuf][Ah0,Ah1,Bh0,Bh1], double-buffered
//    over K-tiles. Staging: linear gload_lds dest + inverse-swizzled global
//    source; ds_read applies the same swizzle.
//    Swizzle: swz(byte) = byte ^ (((byte>>7)&3)<<4)  (involution; XORs row
//    bits 0-1 of the 16-row subtile into the 16B-granule index, so every 8
//    consecutive lanes of a fragment read hit all 8 bank-groups exactly once).
//    grid: (N/256, M/256, nz); B/C advanced by z*SEG.
// ---------------------------------------------------------------------------
#define BARRIER() do { asm volatile("" ::: "memory"); \
                       __builtin_amdgcn_s_barrier(); \
                       asm volatile("" ::: "memory"); } while (0)

template<int OUT_BF16>
__global__ __launch_bounds__(512, 2) void gemm8p(const u16* __restrict__ A,
                                                 const u16* __restrict__ Bbase,
                                                 void* __restrict__ Cv) {
    __shared__ __align__(16) char lds[131072];   // 128 KiB

    const int tid = threadIdx.x;
    const int lane = tid & 63, w = tid >> 6;     // 8 waves
    const int quad = lane >> 4, m16 = lane & 15;
    const int wm = w >> 2, wn = w & 3;           // wave tile: 128 rows x 64 cols
    const int m0 = blockIdx.y * 256, n0 = blockIdx.x * 256;
    const u16* Bp = Bbase + (size_t)blockIdx.z * SEG;

    // --- staging source decode: LDS linear byte p  <-  element at swz(p) ---
    const u16* aSrc[2];
    const u16* bSrc[2];
#pragma unroll
    for (int i = 0; i < 2; ++i) {
        int p = i * 8192 + w * 1024 + lane * 16;           // byte in 16KiB chunk
        int q = p ^ (((p >> 7) & 3) << 4);                  // inverse swizzle
        int rowoff = (q >> 11) * 16 + ((q >> 6) & 15);      // r16g*16 + r
        int coloff = (((q >> 10) & 1) << 5) + ((q & 63) >> 1); // c32g*32 + c
        aSrc[i] = A  + (size_t)(m0 + rowoff) * DIM + coloff;
        bSrc[i] = Bp + (size_t)(n0 + rowoff) * DIM + coloff;
    }
    // per-lane swizzled ds_read byte offset within a chunk
    const int laneoff = m16 * 64 + ((quad * 16) ^ (((m16 >> 1) & 3) << 4));

    f32x4 acc[8][4];
#pragma unroll
    for (int a = 0; a < 8; ++a)
#pragma unroll
        for (int b = 0; b < 4; ++b) acc[a][b] = 0.f;

    bf16x8 af[4][2];   // current m-half fragments (4 mt x 2 ks)
    bf16x8 bfr[4][2];  // all 4 n-frags of this wave (nt x ks)

// chunk ids: (d*4 + 0/1) = A half0/1 ; (d*4 + 2 + 0/1) = B half0/1
#define STAGE_A(d, h, kt) do { int kk_ = ((kt) & 63) * 64;                       \
    gload_lds16(aSrc[0] + (size_t)(h) * (128 * DIM) + kk_,                       \
                lds + ((d) * 4 + (h)) * 16384 + w * 1024);                       \
    gload_lds16(aSrc[1] + (size_t)(h) * (128 * DIM) + kk_,                       \
                lds + ((d) * 4 + (h)) * 16384 + 8192 + w * 1024); } while (0)
#define STAGE_B(d, h, kt) do { int kk_ = ((kt) & 63) * 64;                       \
    gload_lds16(bSrc[0] + (size_t)(h) * (128 * DIM) + kk_,                       \
                lds + ((d) * 4 + 2 + (h)) * 16384 + w * 1024);                   \
    gload_lds16(bSrc[1] + (size_t)(h) * (128 * DIM) + kk_,                       \
                lds + ((d) * 4 + 2 + (h)) * 16384 + 8192 + w * 1024); } while (0)
#define LOAD_A(d, mh) do {                                                       \
    const char* base_ = lds + ((d) * 4 + wm) * 16384 + (mh) * 8192 + laneoff;    \
    _Pragma("unroll") for (int mt = 0; mt < 4; ++mt)                             \
    _Pragma("unroll") for (int ks = 0; ks < 2; ++ks)                             \
        af[mt][ks] = *(const bf16x8*)(base_ + mt * 2048 + ks * 1024); } while (0)
#define LOAD_B(d, nh) do {                                                       \
    const char* base_ = lds + ((d) * 4 + 2 + (wn >> 1)) * 16384                  \
                        + (wn & 1) * 8192 + (nh) * 4096 + laneoff;               \
    _Pragma("unroll") for (int nt = 0; nt < 2; ++nt)                             \
    _Pragma("unroll") for (int ks = 0; ks < 2; ++ks)                             \
        bfr[(nh) * 2 + nt][ks] = *(const bf16x8*)(base_ + nt * 2048 + ks * 1024);\
    } while (0)
#define MFMA_Q(mh, nh) do {                                                      \
    _Pragma("unroll") for (int mt = 0; mt < 4; ++mt)                             \
    _Pragma("unroll") for (int nt = 0; nt < 2; ++nt)                             \
    _Pragma("unroll") for (int ks = 0; ks < 2; ++ks)                             \
        acc[(mh) * 4 + mt][(nh) * 2 + nt] =                                      \
            __builtin_amdgcn_mfma_f32_16x16x32_bf16(                             \
                af[mt][ks], bfr[(nh) * 2 + nt][ks],                              \
                acc[(mh) * 4 + mt][(nh) * 2 + nt], 0, 0, 0); } while (0)

    // prologue: tile0 fully + tile1 B halves; force tile0 landed (residue = t1.B)
    STAGE_B(0, 0, 0); STAGE_B(0, 1, 0); STAGE_A(0, 0, 0); STAGE_A(0, 1, 0);
    STAGE_B(1, 0, 1); STAGE_B(1, 1, 1);
    asm volatile("s_waitcnt vmcnt(4)" ::: "memory");
    BARRIER();

    for (int it = 0; it < 32; ++it) {           // 2 K-tiles / iter, 64 tiles
        const int t = 2 * it;
        // ---- P1: reads tile t (a-lo, b-lo); stage (t+1).Ah0 -> buf1
        LOAD_A(0, 0); LOAD_B(0, 0);
        STAGE_A(1, 0, t + 1);
        asm volatile("s_waitcnt lgkmcnt(8)" ::: "memory");
        BARRIER();
        asm volatile("s_waitcnt lgkmcnt(0)" ::: "memory");
        __builtin_amdgcn_s_setprio(1); MFMA_Q(0, 0); __builtin_amdgcn_s_setprio(0);
        BARRIER();
        // ---- P2: b-hi; stage (t+1).Ah1 -> buf1
        LOAD_B(0, 1);
        STAGE_A(1, 1, t + 1);
        BARRIER();
        asm volatile("s_waitcnt lgkmcnt(0)" ::: "memory");
        __builtin_amdgcn_s_setprio(1); MFMA_Q(0, 1); __builtin_amdgcn_s_setprio(0);
        BARRIER();
        // ---- P3: a-hi; stage (t+2).Bh0 -> buf0 (buf0.B reads done after P2)
        LOAD_A(0, 1);
        STAGE_B(0, 0, t + 2);
        BARRIER();
        asm volatile("s_waitcnt lgkmcnt(0)" ::: "memory");
        __builtin_amdgcn_s_setprio(1); MFMA_Q(1, 1); __builtin_amdgcn_s_setprio(0);
        BARRIER();
        // ---- P4: stage (t+2).Bh1; vmcnt(4) forces tile t+1 fully landed
        STAGE_B(0, 1, t + 2);
        BARRIER();
        __builtin_amdgcn_s_setprio(1); MFMA_Q(1, 0); __builtin_amdgcn_s_setprio(0);
        asm volatile("s_waitcnt vmcnt(4)" ::: "memory");
        BARRIER();
        // ---- P5: reads tile t+1; stage (t+2).Ah0 -> buf0 (buf0.A free after P3)
        LOAD_A(1, 0); LOAD_B(1, 0);
        STAGE_A(0, 0, t + 2);
        asm volatile("s_waitcnt lgkmcnt(8)" ::: "memory");
        BARRIER();
        asm volatile("s_waitcnt lgkmcnt(0)" ::: "memory");
        __builtin_amdgcn_s_setprio(1); MFMA_Q(0, 0); __builtin_amdgcn_s_setprio(0);
        BARRIER();
        // ---- P6: stage (t+2).Ah1
        LOAD_B(1, 1);
        STAGE_A(0, 1, t + 2);
        BARRIER();
        asm volatile("s_waitcnt lgkmcnt(0)" ::: "memory");
        __builtin_amdgcn_s_setprio(1); MFMA_Q(0, 1); __builtin_amdgcn_s_setprio(0);
        BARRIER();
        // ---- P7: stage (t+3).Bh0 -> buf1 (buf1.B reads done after P6)
        LOAD_A(1, 1);
        STAGE_B(1, 0, t + 3);
        BARRIER();
        asm volatile("s_waitcnt lgkmcnt(0)" ::: "memory");
        __builtin_amdgcn_s_setprio(1); MFMA_Q(1, 1); __builtin_amdgcn_s_setprio(0);
        BARRIER();
        // ---- P8: stage (t+3).Bh1; vmcnt(4) forces tile t+2 fully landed
        STAGE_B(1, 1, t + 3);
        BARRIER();
        __builtin_amdgcn_s_setprio(1); MFMA_Q(1, 0); __builtin_amdgcn_s_setprio(0);
        asm volatile("s_waitcnt vmcnt(4)" ::: "memory");
        BARRIER();
    }
    asm volatile("s_waitcnt vmcnt(0)" ::: "memory");  // drain tail garbage stages

#pragma unroll
    for (int mt = 0; mt < 8; ++mt)
#pragma unroll
        for (int nt = 0; nt < 4; ++nt) {
            const int row = m0 + wm * 128 + mt * 16 + quad * 4;
            const int col = n0 + wn * 64 + nt * 16 + m16;
            if (OUT_BF16) {
                u16* C = (u16*)Cv + (size_t)blockIdx.z * SEG;
#pragma unroll
                for (int r = 0; r < 4; ++r)
                    C[(size_t)(row + r) * DIM + col] = f2b(acc[mt][nt][r]);
            } else {
                float* C = (float*)Cv + (size_t)blockIdx.z * SEG;
#pragma unroll
                for (int r = 0; r < 4; ++r)
                    C[(size_t)(row + r) * DIM + col] = acc[mt][nt][r];
            }
        }
#undef STAGE_A
#undef STAGE_B
#undef LOAD_A
#undef LOAD_B
#undef MFMA_Q
}

// ---------------------------------------------------------------------------
// 3) RoPE on xq, xk. Writes q_b, k_b (bf16) and new_hidden[0] (fp32).
// ---------------------------------------------------------------------------
__global__ __launch_bounds__(256) void rope(const u16* __restrict__ XQ,
                                            const u16* __restrict__ XK,
                                            const float* __restrict__ FC,
                                            u16* __restrict__ Qo,
                                            u16* __restrict__ Ko,
                                            float* __restrict__ KH) {
    int tid = blockIdx.x * 256 + threadIdx.x;   // ((b*S+s)*NH+h)*64 + i
    int i = tid & 63;
    int s = (tid >> 11) & 2047;
    float2 cs = *(const float2*)(FC + (s * 64 + i) * 2);
    u32 q = ((const u32*)XQ)[tid];
    u32 k = ((const u32*)XK)[tid];
    float q0 = b2f((u16)(q & 0xffff)), q1 = b2f((u16)(q >> 16));
    float k0 = b2f((u16)(k & 0xffff)), k1 = b2f((u16)(k >> 16));
    float qr = q0 * cs.x - q1 * cs.y, qi = q0 * cs.y + q1 * cs.x;
    float kr = k0 * cs.x - k1 * cs.y, ki = k0 * cs.y + k1 * cs.x;
    ((u32*)Qo)[tid] = (u32)f2b(qr) | ((u32)f2b(qi) << 16);
    ((u32*)Ko)[tid] = (u32)f2b(kr) | ((u32)f2b(ki) << 16);
    *(float2*)(KH + (size_t)tid * 2) = make_float2(kr, ki);
}

// ---------------------------------------------------------------------------
// 4) V prep: new_hidden[1] (fp32) + transposed Vt (bf16, [bh][d][s])
// ---------------------------------------------------------------------------
__global__ __launch_bounds__(256) void vprep(const u16* __restrict__ XV,
                                             float* __restrict__ VH,
                                             u16* __restrict__ VT) {
    __shared__ u16 tile[64][65];
    int bs = blockIdx.x;        // s-tile (32)
    int bd = blockIdx.y;        // d-tile (2)
    int bh = blockIdx.z;        // (64)
    int b = bh >> 5, h = bh & 31;
    int t = threadIdx.x;
    int c = t & 63, r4 = t >> 6;
    for (int i = 0; i < 16; ++i) {
        int sr = i * 4 + r4;
        int gi = ((b * SEQ + bs * 64 + sr) * NH + h) * HD + bd * 64 + c;
        u16 v = XV[gi];
        VH[gi] = b2f(v);
        tile[sr][c] = v;
    }
    __syncthreads();
    for (int i = 0; i < 16; ++i) {
        int dr = i * 4 + r4;
        VT[(bh * HD + bd * 64 + dr) * SEQ + bs * 64 + c] = tile[c][dr];
    }
}

// ---------------------------------------------------------------------------
// 5) Causal flash attention v2.
//    Block = 128 q-rows, 4 waves x 32 rows (2 m-frags). KV tile = 64.
//    K/V staged by global_load_lds (XOR chunk swizzle, unpadded layouts).
// ---------------------------------------------------------------------------
__global__ __launch_bounds__(256, 2) void flash(const u16* __restrict__ Q,
                                                const u16* __restrict__ K,
                                                const u16* __restrict__ Vt,
                                                u16* __restrict__ O) {
    __shared__ __align__(16) u16 k_lds[64 * 128];
    __shared__ __align__(16) u16 v_lds[128 * 64];
    __shared__ __align__(16) u16 p_lds[4][32 * 68];

    const int tid = threadIdx.x, lane = tid & 63, w = tid >> 6;
    const int quad = lane >> 4, m16 = lane & 15;
    const int bh = blockIdx.x;                 // 0..63
    const int b = bh >> 5, h = bh & 31;
    const int qt = (gridDim.y - 1) - blockIdx.y;   // long blocks dispatch first
    const int q0 = qt * 128;
    const int wrow = q0 + w * 32;              // this wave's 32 q-rows

    const int gk = w * 256 + lane;             // K granule base (j adds 64)
    bf16x8 qa[2][4];
#pragma unroll
    for (int mt = 0; mt < 2; ++mt) {
        const u16* qp = Q + ((size_t)(b * SEQ + wrow + mt * 16 + m16) * NH + h) * HD;
#pragma unroll
        for (int ks = 0; ks < 4; ++ks) qa[mt][ks] = *(const bf16x8*)(qp + ks * 32 + quad * 8);
    }

    float mi[2][4], li[2][4];
    f32x4 o[2][8];
#pragma unroll
    for (int mt = 0; mt < 2; ++mt)
#pragma unroll
        for (int r = 0; r < 4; ++r) { mi[mt][r] = -1e30f; li[mt][r] = 0.f; }
#pragma unroll
    for (int mt = 0; mt < 2; ++mt)
#pragma unroll
        for (int n = 0; n < 8; ++n) o[mt][n] = 0.f;

    const float scale = 0.08838834764831845f;   // 1/sqrt(128)
    const int nkt = 2 * qt + 2;

    const u16* Kbase = K + ((size_t)(b * SEQ) * NH + h) * HD;
    const u16* Vbase = Vt + (size_t)(bh * HD) * SEQ;

    for (int kt = 0; kt < nkt; ++kt) {
        const int k0 = kt * 64;
        __syncthreads();
#pragma unroll
        for (int j = 0; j < 4; ++j) {
            int g = gk + j * 64;
            int r = g >> 4, p = g & 15, c = p ^ (r & 15);
            gload_lds16(Kbase + (size_t)(k0 + r) * DIM + c * 8,
                        (char*)k_lds + w * 4096 + j * 1024);
        }
#pragma unroll
        for (int j = 0; j < 4; ++j) {
            int g = gk + j * 64;
            int r = g >> 3, p = g & 7, c = p ^ (r & 7);
            gload_lds16(Vbase + (size_t)r * SEQ + k0 + c * 8,
                        (char*)v_lds + w * 4096 + j * 1024);
        }
        __syncthreads();

        if (k0 > wrow + 31) continue;   // fully-masked for this wave (uniform)

        f32x4 s[2][4];
#pragma unroll
        for (int mt = 0; mt < 2; ++mt)
#pragma unroll
            for (int nt = 0; nt < 4; ++nt) s[mt][nt] = 0.f;
#pragma unroll
        for (int ks = 0; ks < 4; ++ks)
#pragma unroll
            for (int nt = 0; nt < 4; ++nt) {
                int rk = nt * 16 + m16;
                int p = (ks * 4 + quad) ^ m16;
                bf16x8 kb = *(const bf16x8*)(k_lds + rk * 128 + p * 8);
#pragma unroll
                for (int mt = 0; mt < 2; ++mt)
                    s[mt][nt] = __builtin_amdgcn_mfma_f32_16x16x32_bf16(
                        qa[mt][ks], kb, s[mt][nt], 0, 0, 0);
            }

#pragma unroll
        for (int mt = 0; mt < 2; ++mt) {
            float sv[4][4];
            const bool need_mask = (k0 + 63) > (wrow + mt * 16);
#pragma unroll
            for (int nt = 0; nt < 4; ++nt)
#pragma unroll
                for (int r = 0; r < 4; ++r) {
                    float v = s[mt][nt][r] * scale;
                    if (need_mask) {
                        int col = k0 + nt * 16 + m16;
                        int rq = wrow + mt * 16 + quad * 4 + r;
                        if (col > rq) v = -1e30f;
                    }
                    sv[nt][r] = v;
                }
#pragma unroll
            for (int r = 0; r < 4; ++r) {
                float mx = fmaxf(fmaxf(sv[0][r], sv[1][r]), fmaxf(sv[2][r], sv[3][r]));
#pragma unroll
                for (int off = 8; off >= 1; off >>= 1) mx = fmaxf(mx, __shfl_xor(mx, off));
                float mnew = fmaxf(mi[mt][r], mx);
                float alpha = __expf(mi[mt][r] - mnew);
                float sum = 0.f;
#pragma unroll
                for (int nt = 0; nt < 4; ++nt) {
                    float pv = __expf(sv[nt][r] - mnew);
                    sum += pv;
                    p_lds[w][(mt * 16 + quad * 4 + r) * 68 + nt * 16 + m16] = f2b(pv);
                }
#pragma unroll
                for (int off = 8; off >= 1; off >>= 1) sum += __shfl_xor(sum, off);
                li[mt][r] = li[mt][r] * alpha + sum;
                mi[mt][r] = mnew;
#pragma unroll
                for (int n8 = 0; n8 < 8; ++n8) o[mt][n8][r] *= alpha;
            }
        }

        asm volatile("s_waitcnt lgkmcnt(0)" ::: "memory");

#pragma unroll
        for (int ks2 = 0; ks2 < 2; ++ks2) {
            bf16x8 pa[2];
#pragma unroll
            for (int mt = 0; mt < 2; ++mt)
                pa[mt] = *(const bf16x8*)(&p_lds[w][0] + (mt * 16 + m16) * 68 + ks2 * 32 + quad * 8);
#pragma unroll
            for (int n8 = 0; n8 < 8; ++n8) {
                int rv = n8 * 16 + m16;
                int p = (ks2 * 4 + quad) ^ (m16 & 7);
                bf16x8 vb = *(const bf16x8*)(v_lds + rv * 64 + p * 8);
#pragma unroll
                for (int mt = 0; mt < 2; ++mt)
                    o[mt][n8] = __builtin_amdgcn_mfma_f32_16x16x32_bf16(
                        pa[mt], vb, o[mt][n8], 0, 0, 0);
            }
        }
    }

#pragma unroll
    for (int mt = 0; mt < 2; ++mt) {
        float inv[4];
#pragma unroll
        for (int r = 0; r < 4; ++r) inv[r] = 1.0f / li[mt][r];
#pragma unroll
        for (int n8 = 0; n8 < 8; ++n8)
#pragma unroll
            for (int r = 0; r < 4; ++r) {
                int rq = wrow + mt * 16 + quad * 4 + r;
                O[((size_t)(b * SEQ + rq) * NH + h) * HD + n8 * 16 + m16] =
                    f2b(o[mt][n8][r] * inv[r]);
            }
    }
}

// ---------------------------------------------------------------------------
// launch — ws layout (bf16 elems, SEG each):
//  0: x_b (→ q_rope)  1: wq_b (→ k_rope)  2: wk_b (→ Vt)  3: wv_b (→ attn_out)
//  4: wo_b  5: xq_b  6: xk_b  7: xv_b
// ---------------------------------------------------------------------------
extern "C" void kernel_launch(void* const* d_in, const int* in_sizes, int n_in,
                              void* d_out, int out_size, void* d_ws, size_t ws_size,
                              hipStream_t stream) {
    const float* x  = (const float*)d_in[0];
    const float* fc = (const float*)d_in[1];
    const float* wq = (const float*)d_in[4];
    const float* wk = (const float*)d_in[5];
    const float* wv = (const float*)d_in[6];
    const float* wo = (const float*)d_in[7];

    float* out = (float*)d_out;
    float* kh  = out + 16777216;             // new_hidden[0]
    float* vh  = out + 33554432;             // new_hidden[1]

    u16* ws = (u16*)d_ws;
    u16* xb  = ws + 0L * SEG;
    u16* wqb = ws + 1L * SEG;
    u16* wkb = ws + 2L * SEG;
    u16* wvb = ws + 3L * SEG;
    u16* wob = ws + 4L * SEG;
    u16* xqb = ws + 5L * SEG;
    u16* xkb = ws + 6L * SEG;
    u16* xvb = ws + 7L * SEG;
    u16* qro = xb;    // q after rope
    u16* kro = wqb;   // k after rope
    u16* vt  = wkb;   // transposed V
    u16* ao  = wvb;   // attention output

    cast5<<<dim3(81920), dim3(256), 0, stream>>>(x, wq, wk, wv, wo, ws);
    gemm8p<1><<<dim3(16, 16, 3), dim3(512), 0, stream>>>(xb, wqb, (void*)xqb);
    rope<<<dim3(32768), dim3(256), 0, stream>>>(xqb, xkb, fc, qro, kro, kh);
    vprep<<<dim3(32, 2, 64), dim3(256), 0, stream>>>(xvb, vh, vt);
    flash<<<dim3(64, 16), dim3(256), 0, stream>>>(qro, kro, vt, ao);
    gemm8p<0><<<dim3(16, 16, 1), dim3(512), 0, stream>>>(ao, wob, (void*)out);
}